// Round 1
// baseline (2584.735 us; speedup 1.0000x reference)
//
#include <hip/hip_runtime.h>
#include <hip/hip_bf16.h>
#include <cstdint>
#include <cstddef>

#define DEPTH 6
#define DIM   1024
#define HEADS 16
#define DIMH  64
#define INNER 1024
#define DFF   4096
#define SEQ   2048
#define NTOK  4096   // 2 * 2048

typedef __attribute__((ext_vector_type(8))) short bf16x8;
typedef __attribute__((ext_vector_type(4))) float f32x4;
typedef __hip_bfloat16 bf16;

__device__ __forceinline__ void gld_lds16(const void* g, void* l) {
  __builtin_amdgcn_global_load_lds(
      (const __attribute__((address_space(1))) unsigned int*)g,
      (__attribute__((address_space(3))) unsigned int*)l,
      16, 0, 0);
}

// ---------------------------------------------------------------------------
// Weight transpose + fp32->bf16 convert: in [D][K][N] -> out [D][orows][K]
// (rows row0..row0+N-1 of out). 32x32 tiles via LDS.
// ---------------------------------------------------------------------------
__global__ __launch_bounds__(256) void transpose_convert(
    const float* __restrict__ in, bf16* __restrict__ out,
    int K, int N, int row0, int orows)
{
  __shared__ float tile[32][33];
  const int d  = blockIdx.z;
  const int n0 = blockIdx.x * 32, k0 = blockIdx.y * 32;
  const int c = threadIdx.x & 31, rb = threadIdx.x >> 5;  // 8 rows per pass
  const float* src = in + ((size_t)d * K + k0) * N + n0;
#pragma unroll
  for (int rr = 0; rr < 4; ++rr) {
    int r = rb + rr * 8;                  // k-local
    tile[r][c] = src[(size_t)r * N + c];
  }
  __syncthreads();
  bf16* dst = out + ((size_t)d * orows + row0 + n0) * K + k0;
#pragma unroll
  for (int rr = 0; rr < 4; ++rr) {
    int r = rb + rr * 8;                  // n-local
    dst[(size_t)r * K + c] = __float2bfloat16(tile[c][r]);
  }
}

// ---------------------------------------------------------------------------
// LayerNorm: x fp32 [NTOK][DIM] -> h bf16. One block (256 thr) per row.
// ---------------------------------------------------------------------------
__global__ __launch_bounds__(256) void ln_kernel(
    const float* __restrict__ x, const float* __restrict__ g,
    const float* __restrict__ b, bf16* __restrict__ h)
{
  const int row = blockIdx.x;
  const int tid = threadIdx.x;
  const float4 xv = *(const float4*)(x + (size_t)row * DIM + tid * 4);
  float s  = xv.x + xv.y + xv.z + xv.w;
  float s2 = xv.x * xv.x + xv.y * xv.y + xv.z * xv.z + xv.w * xv.w;
#pragma unroll
  for (int off = 1; off < 64; off <<= 1) {
    s  += __shfl_xor(s, off);
    s2 += __shfl_xor(s2, off);
  }
  __shared__ float red[8];
  const int wave = tid >> 6, lane = tid & 63;
  if (lane == 0) { red[wave * 2] = s; red[wave * 2 + 1] = s2; }
  __syncthreads();
  const float ts  = red[0] + red[2] + red[4] + red[6];
  const float ts2 = red[1] + red[3] + red[5] + red[7];
  const float mu  = ts * (1.0f / DIM);
  const float var = ts2 * (1.0f / DIM) - mu * mu;
  const float rstd = rsqrtf(var + 1e-5f);
  const float4 gv = *(const float4*)(g + tid * 4);
  const float4 bv = *(const float4*)(b + tid * 4);
  bf16 hv[4];
  hv[0] = __float2bfloat16((xv.x - mu) * rstd * gv.x + bv.x);
  hv[1] = __float2bfloat16((xv.y - mu) * rstd * gv.y + bv.y);
  hv[2] = __float2bfloat16((xv.z - mu) * rstd * gv.z + bv.z);
  hv[3] = __float2bfloat16((xv.w - mu) * rstd * gv.w + bv.w);
  *(uint2*)(h + (size_t)row * DIM + tid * 4) = *(uint2*)hv;
}

// ---------------------------------------------------------------------------
// GEMM: C[M,N] = A[M,K](bf16,row-major) x Bt[N,K](bf16, = B^T).
// 128x128 tile, BK=64, 4 waves (2x2), 16x16x32 MFMA, global_load_lds + XOR
// swizzle (16B chunk ^ (row&7)) to avoid 128B-stride bank conflicts.
// EPI 0: QKV split -> q[bh][n][64], k[bh][n][64], vt[bh][64][n] (bf16)
// EPI 1: outf[row*N+col] = acc + bias[col] + outf[...]   (fp32 residual)
// EPI 2: outb = bf16(gelu_exact(acc + bias[col]))
// ---------------------------------------------------------------------------
template<int EPI>
__global__ __launch_bounds__(256) void gemm128(
    const bf16* __restrict__ A, const bf16* __restrict__ Bt,
    int N, int K,
    const float* __restrict__ bias,
    float* __restrict__ outf, bf16* __restrict__ outb,
    bf16* __restrict__ outq, bf16* __restrict__ outk, bf16* __restrict__ outvt)
{
  __shared__ alignas(16) bf16 As[128 * 64];
  __shared__ alignas(16) bf16 Bs[128 * 64];
  const int tid  = threadIdx.x;
  const int lane = tid & 63;
  const int wave = tid >> 6;
  const int wr = wave >> 1, wc = wave & 1;
  const int m0 = blockIdx.y * 128, n0 = blockIdx.x * 128;
  const int sr = tid >> 3, pc = tid & 7;
  const int wbase = (tid & ~63) << 4;   // byte offset of this wave's slot group

  f32x4 acc[4][4];
#pragma unroll
  for (int m = 0; m < 4; ++m)
#pragma unroll
    for (int n = 0; n < 4; ++n) acc[m][n] = (f32x4){0.f, 0.f, 0.f, 0.f};

  for (int k0 = 0; k0 < K; k0 += 64) {
#pragma unroll
    for (int it = 0; it < 4; ++it) {
      const int r  = it * 32 + sr;
      const int lc = pc ^ (r & 7);
      gld_lds16(A  + (size_t)(m0 + r) * K + k0 + lc * 8, (char*)As + it * 4096 + wbase);
      gld_lds16(Bt + (size_t)(n0 + r) * K + k0 + lc * 8, (char*)Bs + it * 4096 + wbase);
    }
    __syncthreads();
#pragma unroll
    for (int kk = 0; kk < 2; ++kk) {
      const int cb = kk * 4 + (lane >> 4);
      bf16x8 af[4], bfr[4];
#pragma unroll
      for (int m = 0; m < 4; ++m) {
        const int r = wr * 64 + m * 16 + (lane & 15);
        af[m] = *(const bf16x8*)((const char*)As + r * 128 + ((cb ^ (r & 7)) << 4));
      }
#pragma unroll
      for (int n = 0; n < 4; ++n) {
        const int r = wc * 64 + n * 16 + (lane & 15);
        bfr[n] = *(const bf16x8*)((const char*)Bs + r * 128 + ((cb ^ (r & 7)) << 4));
      }
#pragma unroll
      for (int m = 0; m < 4; ++m)
#pragma unroll
        for (int n = 0; n < 4; ++n)
          acc[m][n] = __builtin_amdgcn_mfma_f32_16x16x32_bf16(af[m], bfr[n], acc[m][n], 0, 0, 0);
    }
    __syncthreads();
  }

#pragma unroll
  for (int m = 0; m < 4; ++m) {
    const int rb = m0 + wr * 64 + m * 16 + ((lane >> 4) << 2);
#pragma unroll
    for (int n = 0; n < 4; ++n) {
      const int col = n0 + wc * 64 + n * 16 + (lane & 15);
#pragma unroll
      for (int j = 0; j < 4; ++j) {
        const int row = rb + j;
        const float v = acc[m][n][j];
        if (EPI == 0) {
          const int batch = row >> 11, tok = row & 2047;
          const bf16 bv = __float2bfloat16(v);
          if (col < 1024) {
            outq[(((size_t)(batch * HEADS + (col >> 6))) * SEQ + tok) * DIMH + (col & 63)] = bv;
          } else if (col < 2048) {
            const int c = col - 1024;
            outk[(((size_t)(batch * HEADS + (c >> 6))) * SEQ + tok) * DIMH + (c & 63)] = bv;
          } else {
            const int c = col - 2048;
            outvt[(((size_t)(batch * HEADS + (c >> 6))) * DIMH + (c & 63)) * SEQ + tok] = bv;
          }
        } else if (EPI == 1) {
          const size_t off = (size_t)row * N + col;
          outf[off] = v + bias[col] + outf[off];
        } else {
          const float t = v + bias[col];
          const float gg = 0.5f * t * (1.0f + erff(t * 0.70710678118654752f));
          outb[(size_t)row * N + col] = __float2bfloat16(gg);
        }
      }
    }
  }
}

// ---------------------------------------------------------------------------
// Flash attention. Block = 4 waves x 32 q-rows (QBLK=128). KVBLK=64.
// q,k: [bh][n][64] bf16 ; vt: [bh][64][n] bf16 ; out: [tok][INNER] bf16.
// Online softmax in exp2 domain. P goes through per-wave swizzled LDS.
// ---------------------------------------------------------------------------
__global__ __launch_bounds__(256) void attn_kernel(
    const bf16* __restrict__ q, const bf16* __restrict__ k,
    const bf16* __restrict__ vt, bf16* __restrict__ out)
{
  __shared__ alignas(16) bf16 Ks[64 * 64];
  __shared__ alignas(16) bf16 Vs[64 * 64];
  __shared__ alignas(16) bf16 Ps[4][32 * 64];
  const int tid  = threadIdx.x;
  const int lane = tid & 63;
  const int wave = tid >> 6;
  const int bh   = blockIdx.y;
  const int qw   = blockIdx.x * 128 + wave * 32;
  const int sr = tid >> 3, pc = tid & 7;
  const int wbase = (tid & ~63) << 4;

  const bf16* qb = q + (size_t)bh * SEQ * DIMH;
  bf16x8 qf[2][2];
#pragma unroll
  for (int m = 0; m < 2; ++m)
#pragma unroll
    for (int kk = 0; kk < 2; ++kk)
      qf[m][kk] = *(const bf16x8*)(qb + (size_t)(qw + m * 16 + (lane & 15)) * DIMH
                                   + kk * 32 + ((lane >> 4) << 3));

  f32x4 ao[2][4];
  float mst[2][4], lst[2][4];
#pragma unroll
  for (int m = 0; m < 2; ++m)
#pragma unroll
    for (int n = 0; n < 4; ++n) ao[m][n] = (f32x4){0.f, 0.f, 0.f, 0.f};
#pragma unroll
  for (int m = 0; m < 2; ++m)
#pragma unroll
    for (int jj = 0; jj < 4; ++jj) { mst[m][jj] = -INFINITY; lst[m][jj] = 0.f; }

  const float cs = 0.125f * 1.44269504088896f;  // SCALE * log2(e)

  for (int jt = 0; jt < SEQ / 64; ++jt) {
#pragma unroll
    for (int it = 0; it < 2; ++it) {
      const int r  = it * 32 + sr;
      const int lc = pc ^ (r & 7);
      gld_lds16(k  + ((size_t)bh * SEQ + jt * 64 + r) * DIMH + lc * 8,
                (char*)Ks + it * 4096 + wbase);
      gld_lds16(vt + ((size_t)bh * DIMH + r) * SEQ + jt * 64 + lc * 8,
                (char*)Vs + it * 4096 + wbase);
    }
    __syncthreads();

    // S = Q K^T  (per-wave 32x64)
    f32x4 sa[2][4];
#pragma unroll
    for (int m = 0; m < 2; ++m)
#pragma unroll
      for (int n = 0; n < 4; ++n) sa[m][n] = (f32x4){0.f, 0.f, 0.f, 0.f};
#pragma unroll
    for (int kk = 0; kk < 2; ++kk) {
      const int cb = kk * 4 + (lane >> 4);
      bf16x8 bk[4];
#pragma unroll
      for (int n = 0; n < 4; ++n) {
        const int r = n * 16 + (lane & 15);
        bk[n] = *(const bf16x8*)((const char*)Ks + r * 128 + ((cb ^ (r & 7)) << 4));
      }
#pragma unroll
      for (int m = 0; m < 2; ++m)
#pragma unroll
        for (int n = 0; n < 4; ++n)
          sa[m][n] = __builtin_amdgcn_mfma_f32_16x16x32_bf16(qf[m][kk], bk[n], sa[m][n], 0, 0, 0);
    }

    // online softmax + P -> LDS (bf16, swizzled)
#pragma unroll
    for (int m = 0; m < 2; ++m) {
#pragma unroll
      for (int jj = 0; jj < 4; ++jj) {
        const float s0 = sa[m][0][jj] * cs, s1 = sa[m][1][jj] * cs;
        const float s2 = sa[m][2][jj] * cs, s3 = sa[m][3][jj] * cs;
        float mx = fmaxf(fmaxf(s0, s1), fmaxf(s2, s3));
#pragma unroll
        for (int off = 1; off < 16; off <<= 1) mx = fmaxf(mx, __shfl_xor(mx, off));
        const float mo = mst[m][jj];
        const float m2 = fmaxf(mo, mx);
        const float corr = exp2f(mo - m2);
        float pv4[4];
        pv4[0] = exp2f(s0 - m2); pv4[1] = exp2f(s1 - m2);
        pv4[2] = exp2f(s2 - m2); pv4[3] = exp2f(s3 - m2);
        float rs = pv4[0] + pv4[1] + pv4[2] + pv4[3];
#pragma unroll
        for (int off = 1; off < 16; off <<= 1) rs += __shfl_xor(rs, off);
        mst[m][jj] = m2;
        lst[m][jj] = lst[m][jj] * corr + rs;
#pragma unroll
        for (int n = 0; n < 4; ++n) ao[m][n][jj] *= corr;
        const int prow = m * 16 + ((lane >> 4) << 2) + jj;
        char* pb = (char*)&Ps[wave][0] + prow * 128;
        const int colb = lane & 15;
#pragma unroll
        for (int n = 0; n < 4; ++n) {
          const int col = n * 16 + colb;
          *(bf16*)(pb + (((col >> 3) ^ (prow & 7)) << 4) + ((col & 7) << 1)) =
              __float2bfloat16(pv4[n]);
        }
      }
    }

    // O += P * V
#pragma unroll
    for (int kk = 0; kk < 2; ++kk) {
      const int cb = kk * 4 + (lane >> 4);
      bf16x8 pa[2], vb[4];
#pragma unroll
      for (int m = 0; m < 2; ++m) {
        const int r = m * 16 + (lane & 15);
        pa[m] = *(const bf16x8*)((const char*)&Ps[wave][0] + r * 128 + ((cb ^ (r & 7)) << 4));
      }
#pragma unroll
      for (int n = 0; n < 4; ++n) {
        const int r = n * 16 + (lane & 15);
        vb[n] = *(const bf16x8*)((const char*)Vs + r * 128 + ((cb ^ (r & 7)) << 4));
      }
#pragma unroll
      for (int m = 0; m < 2; ++m)
#pragma unroll
        for (int n = 0; n < 4; ++n)
          ao[m][n] = __builtin_amdgcn_mfma_f32_16x16x32_bf16(pa[m], vb[n], ao[m][n], 0, 0, 0);
    }
    __syncthreads();
  }

  const int batch = bh >> 4, head = bh & 15;
#pragma unroll
  for (int m = 0; m < 2; ++m)
#pragma unroll
    for (int jj = 0; jj < 4; ++jj) {
      const float inv = 1.0f / lst[m][jj];
      const int row = qw + m * 16 + ((lane >> 4) << 2) + jj;
#pragma unroll
      for (int n = 0; n < 4; ++n) {
        const int d = n * 16 + (lane & 15);
        out[((size_t)batch * SEQ + row) * INNER + head * DIMH + d] =
            __float2bfloat16(ao[m][n][jj] * inv);
      }
    }
}

// ---------------------------------------------------------------------------
extern "C" void kernel_launch(void* const* d_in, const int* in_sizes, int n_in,
                              void* d_out, int out_size, void* d_ws, size_t ws_size,
                              hipStream_t stream)
{
  (void)in_sizes; (void)n_in; (void)out_size; (void)ws_size;
  const float* x_in = (const float*)d_in[0];
  const float* Wq   = (const float*)d_in[1];
  const float* Wkv  = (const float*)d_in[2];
  const float* Wo   = (const float*)d_in[3];
  const float* bo   = (const float*)d_in[4];
  const float* ln1g = (const float*)d_in[5];
  const float* ln1b = (const float*)d_in[6];
  const float* ln2g = (const float*)d_in[7];
  const float* ln2b = (const float*)d_in[8];
  const float* W1   = (const float*)d_in[9];
  const float* b1   = (const float*)d_in[10];
  const float* W2   = (const float*)d_in[11];
  const float* b2   = (const float*)d_in[12];
  float* xb = (float*)d_out;

  char* ws = (char*)d_ws;
  size_t off = 0;
  auto take = [&](size_t bytes) {
    char* p = ws + off;
    off += (bytes + 255) & ~(size_t)255;
    return p;
  };
  bf16* Wqkvt = (bf16*)take((size_t)DEPTH * 3072 * 1024 * 2);
  bf16* Wot   = (bf16*)take((size_t)DEPTH * 1024 * 1024 * 2);
  bf16* W1t   = (bf16*)take((size_t)DEPTH * 4096 * 1024 * 2);
  bf16* W2t   = (bf16*)take((size_t)DEPTH * 1024 * 4096 * 2);
  bf16* hb    = (bf16*)take((size_t)NTOK * DIM * 2);
  bf16* qbuf  = (bf16*)take((size_t)NTOK * INNER * 2);
  bf16* kbuf  = (bf16*)take((size_t)NTOK * INNER * 2);
  bf16* vtbuf = (bf16*)take((size_t)NTOK * INNER * 2);
  bf16* aobuf = (bf16*)take((size_t)NTOK * INNER * 2);
  bf16* h1buf = (bf16*)take((size_t)NTOK * DFF * 2);

  hipMemcpyAsync(xb, x_in, (size_t)NTOK * DIM * 4, hipMemcpyDeviceToDevice, stream);

  dim3 b256(256);
  transpose_convert<<<dim3(32, 32, DEPTH),  b256, 0, stream>>>(Wq,  Wqkvt, 1024, 1024, 0,    3072);
  transpose_convert<<<dim3(64, 32, DEPTH),  b256, 0, stream>>>(Wkv, Wqkvt, 1024, 2048, 1024, 3072);
  transpose_convert<<<dim3(32, 32, DEPTH),  b256, 0, stream>>>(Wo,  Wot,   1024, 1024, 0,    1024);
  transpose_convert<<<dim3(128, 32, DEPTH), b256, 0, stream>>>(W1,  W1t,   1024, 4096, 0,    4096);
  transpose_convert<<<dim3(32, 128, DEPTH), b256, 0, stream>>>(W2,  W2t,   4096, 1024, 0,    1024);

  for (int l = 0; l < DEPTH; ++l) {
    ln_kernel<<<NTOK, b256, 0, stream>>>(xb, ln1g + l * DIM, ln1b + l * DIM, hb);
    gemm128<0><<<dim3(3072 / 128, NTOK / 128), b256, 0, stream>>>(
        hb, Wqkvt + (size_t)l * 3072 * 1024, 3072, 1024,
        nullptr, nullptr, nullptr, qbuf, kbuf, vtbuf);
    attn_kernel<<<dim3(SEQ / 128, 32), b256, 0, stream>>>(qbuf, kbuf, vtbuf, aobuf);
    gemm128<1><<<dim3(1024 / 128, NTOK / 128), b256, 0, stream>>>(
        aobuf, Wot + (size_t)l * 1024 * 1024, 1024, 1024,
        bo + l * DIM, xb, nullptr, nullptr, nullptr, nullptr);
    ln_kernel<<<NTOK, b256, 0, stream>>>(xb, ln2g + l * DIM, ln2b + l * DIM, hb);
    gemm128<2><<<dim3(4096 / 128, NTOK / 128), b256, 0, stream>>>(
        hb, W1t + (size_t)l * 4096 * 1024, 4096, 1024,
        b1 + l * DFF, nullptr, h1buf, nullptr, nullptr, nullptr);
    gemm128<1><<<dim3(1024 / 128, NTOK / 128), b256, 0, stream>>>(
        h1buf, W2t + (size_t)l * 1024 * 4096, 1024, 4096,
        b2 + l * DIM, xb, nullptr, nullptr, nullptr, nullptr);
  }
}

// Round 2
// 2017.821 us; speedup vs baseline: 1.2810x; 1.2810x over previous
//
#include <hip/hip_runtime.h>
#include <hip/hip_bf16.h>
#include <cstdint>
#include <cstddef>

#define DEPTH 6
#define DIM   1024
#define HEADS 16
#define DIMH  64
#define INNER 1024
#define DFF   4096
#define SEQ   2048
#define NTOK  4096   // 2 * 2048

typedef __attribute__((ext_vector_type(8))) short bf16x8;
typedef __attribute__((ext_vector_type(4))) short bf16x4;
typedef __attribute__((ext_vector_type(4))) float f32x4;
typedef __hip_bfloat16 bf16;

#define CS 0.18033688011112042f  // SCALE * log2(e)

__device__ __forceinline__ void gld_lds16(const void* g, void* l) {
  __builtin_amdgcn_global_load_lds(
      (const __attribute__((address_space(1))) unsigned int*)g,
      (__attribute__((address_space(3))) unsigned int*)l,
      16, 0, 0);
}

// ---------------------------------------------------------------------------
// Weight transpose + fp32->bf16 convert: in [D][K][N] -> out [D][orows][K]
// ---------------------------------------------------------------------------
__global__ __launch_bounds__(256) void transpose_convert(
    const float* __restrict__ in, bf16* __restrict__ out,
    int K, int N, int row0, int orows)
{
  __shared__ float tile[32][33];
  const int d  = blockIdx.z;
  const int n0 = blockIdx.x * 32, k0 = blockIdx.y * 32;
  const int c = threadIdx.x & 31, rb = threadIdx.x >> 5;
  const float* src = in + ((size_t)d * K + k0) * N + n0;
#pragma unroll
  for (int rr = 0; rr < 4; ++rr) {
    int r = rb + rr * 8;
    tile[r][c] = src[(size_t)r * N + c];
  }
  __syncthreads();
  bf16* dst = out + ((size_t)d * orows + row0 + n0) * K + k0;
#pragma unroll
  for (int rr = 0; rr < 4; ++rr) {
    int r = rb + rr * 8;
    dst[(size_t)r * K + c] = __float2bfloat16(tile[c][r]);
  }
}

// ---------------------------------------------------------------------------
// LayerNorm: x fp32 [NTOK][DIM] -> h bf16. One block (256 thr) per row.
// ---------------------------------------------------------------------------
__global__ __launch_bounds__(256) void ln_kernel(
    const float* __restrict__ x, const float* __restrict__ g,
    const float* __restrict__ b, bf16* __restrict__ h)
{
  const int row = blockIdx.x;
  const int tid = threadIdx.x;
  const float4 xv = *(const float4*)(x + (size_t)row * DIM + tid * 4);
  float s  = xv.x + xv.y + xv.z + xv.w;
  float s2 = xv.x * xv.x + xv.y * xv.y + xv.z * xv.z + xv.w * xv.w;
#pragma unroll
  for (int off = 1; off < 64; off <<= 1) {
    s  += __shfl_xor(s, off);
    s2 += __shfl_xor(s2, off);
  }
  __shared__ float red[8];
  const int wave = tid >> 6, lane = tid & 63;
  if (lane == 0) { red[wave * 2] = s; red[wave * 2 + 1] = s2; }
  __syncthreads();
  const float ts  = red[0] + red[2] + red[4] + red[6];
  const float ts2 = red[1] + red[3] + red[5] + red[7];
  const float mu  = ts * (1.0f / DIM);
  const float var = ts2 * (1.0f / DIM) - mu * mu;
  const float rstd = rsqrtf(var + 1e-5f);
  const float4 gv = *(const float4*)(g + tid * 4);
  const float4 bv = *(const float4*)(b + tid * 4);
  bf16 hv[4];
  hv[0] = __float2bfloat16((xv.x - mu) * rstd * gv.x + bv.x);
  hv[1] = __float2bfloat16((xv.y - mu) * rstd * gv.y + bv.y);
  hv[2] = __float2bfloat16((xv.z - mu) * rstd * gv.z + bv.z);
  hv[3] = __float2bfloat16((xv.w - mu) * rstd * gv.w + bv.w);
  *(uint2*)(h + (size_t)row * DIM + tid * 4) = *(uint2*)hv;
}

// ---------------------------------------------------------------------------
// GEMM: C[M,N] = A[M,K](bf16,row-major) x Bt[N,K](bf16, = B^T).
// 128x128 tile, BK=64, 4 waves (2x2), 16x16x32 MFMA, global_load_lds + XOR
// swizzle. EPI 0: QKV split (q pre-scaled by CS); EPI 1: +bias+residual fp32;
// EPI 2: bf16 gelu.
// ---------------------------------------------------------------------------
template<int EPI>
__global__ __launch_bounds__(256) void gemm128(
    const bf16* __restrict__ A, const bf16* __restrict__ Bt,
    int N, int K,
    const float* __restrict__ bias,
    float* __restrict__ outf, bf16* __restrict__ outb,
    bf16* __restrict__ outq, bf16* __restrict__ outk, bf16* __restrict__ outvt)
{
  __shared__ alignas(16) bf16 As[128 * 64];
  __shared__ alignas(16) bf16 Bs[128 * 64];
  const int tid  = threadIdx.x;
  const int lane = tid & 63;
  const int wave = tid >> 6;
  const int wr = wave >> 1, wc = wave & 1;
  const int m0 = blockIdx.y * 128, n0 = blockIdx.x * 128;
  const int sr = tid >> 3, pc = tid & 7;
  const int wbase = (tid & ~63) << 4;

  f32x4 acc[4][4];
#pragma unroll
  for (int m = 0; m < 4; ++m)
#pragma unroll
    for (int n = 0; n < 4; ++n) acc[m][n] = (f32x4){0.f, 0.f, 0.f, 0.f};

  for (int k0 = 0; k0 < K; k0 += 64) {
#pragma unroll
    for (int it = 0; it < 4; ++it) {
      const int r  = it * 32 + sr;
      const int lc = pc ^ (r & 7);
      gld_lds16(A  + (size_t)(m0 + r) * K + k0 + lc * 8, (char*)As + it * 4096 + wbase);
      gld_lds16(Bt + (size_t)(n0 + r) * K + k0 + lc * 8, (char*)Bs + it * 4096 + wbase);
    }
    __syncthreads();
#pragma unroll
    for (int kk = 0; kk < 2; ++kk) {
      const int cb = kk * 4 + (lane >> 4);
      bf16x8 af[4], bfr[4];
#pragma unroll
      for (int m = 0; m < 4; ++m) {
        const int r = wr * 64 + m * 16 + (lane & 15);
        af[m] = *(const bf16x8*)((const char*)As + r * 128 + ((cb ^ (r & 7)) << 4));
      }
#pragma unroll
      for (int n = 0; n < 4; ++n) {
        const int r = wc * 64 + n * 16 + (lane & 15);
        bfr[n] = *(const bf16x8*)((const char*)Bs + r * 128 + ((cb ^ (r & 7)) << 4));
      }
#pragma unroll
      for (int m = 0; m < 4; ++m)
#pragma unroll
        for (int n = 0; n < 4; ++n)
          acc[m][n] = __builtin_amdgcn_mfma_f32_16x16x32_bf16(af[m], bfr[n], acc[m][n], 0, 0, 0);
    }
    __syncthreads();
  }

#pragma unroll
  for (int m = 0; m < 4; ++m) {
    const int rb = m0 + wr * 64 + m * 16 + ((lane >> 4) << 2);
#pragma unroll
    for (int n = 0; n < 4; ++n) {
      const int col = n0 + wc * 64 + n * 16 + (lane & 15);
#pragma unroll
      for (int j = 0; j < 4; ++j) {
        const int row = rb + j;
        const float v = acc[m][n][j];
        if (EPI == 0) {
          const int batch = row >> 11, tok = row & 2047;
          if (col < 1024) {
            outq[(((size_t)(batch * HEADS + (col >> 6))) * SEQ + tok) * DIMH + (col & 63)] =
                __float2bfloat16(v * CS);
          } else if (col < 2048) {
            const int c = col - 1024;
            outk[(((size_t)(batch * HEADS + (c >> 6))) * SEQ + tok) * DIMH + (c & 63)] =
                __float2bfloat16(v);
          } else {
            const int c = col - 2048;
            outvt[(((size_t)(batch * HEADS + (c >> 6))) * DIMH + (c & 63)) * SEQ + tok] =
                __float2bfloat16(v);
          }
        } else if (EPI == 1) {
          const size_t off = (size_t)row * N + col;
          outf[off] = v + bias[col] + outf[off];
        } else {
          const float t = v + bias[col];
          const float gg = 0.5f * t * (1.0f + erff(t * 0.70710678118654752f));
          outb[(size_t)row * N + col] = __float2bfloat16(gg);
        }
      }
    }
  }
}

// ---------------------------------------------------------------------------
// Flash attention, swapped-QK^T structure. 4 waves x 32 q-rows (QBLK=128),
// KVBLK=64, double-buffered K/V staging. S^T = mfma(K, Q) puts a full q-row's
// scores lane-local: softmax = 2 shfl_xor per 32 rows; P stays in registers
// (sigma-permuted PV: V read as 2x ds_read_b64 matching the lane-local k
// order). Q pre-scaled by CS; defer-max (THR=11 in exp2 domain).
// ---------------------------------------------------------------------------
__global__ __launch_bounds__(256) void attn_kernel(
    const bf16* __restrict__ q, const bf16* __restrict__ k,
    const bf16* __restrict__ vt, bf16* __restrict__ out)
{
  __shared__ alignas(16) bf16 Ks[2][64 * 64];
  __shared__ alignas(16) bf16 Vs[2][64 * 64];
  const int tid  = threadIdx.x;
  const int lane = tid & 63;
  const int wave = tid >> 6;
  const int g    = lane >> 4;
  const int lm   = lane & 15;
  const int bh   = blockIdx.y;
  const int qw   = blockIdx.x * 128 + wave * 32;
  const int sr = tid >> 3, pc = tid & 7;
  const int wbase = (tid & ~63) << 4;

  // Q as B-operand fragments: lane holds Q[qw+m*16+lm][kk*32 + g*8 + 0..7]
  bf16x8 qf[2][2];
#pragma unroll
  for (int m = 0; m < 2; ++m)
#pragma unroll
    for (int kk = 0; kk < 2; ++kk)
      qf[m][kk] = *(const bf16x8*)(q + ((size_t)bh * SEQ + qw + m * 16 + lm) * DIMH
                                   + kk * 32 + g * 8);

  f32x4 ao[2][4];
#pragma unroll
  for (int m = 0; m < 2; ++m)
#pragma unroll
    for (int n = 0; n < 4; ++n) ao[m][n] = (f32x4){0.f, 0.f, 0.f, 0.f};
  float mrow[2] = {-INFINITY, -INFINITY};
  float lrow[2] = {0.f, 0.f};

  auto stage = [&](int jt, int buf) {
#pragma unroll
    for (int it = 0; it < 2; ++it) {
      const int r  = it * 32 + sr;
      const int lc = pc ^ (r & 7);
      gld_lds16(k  + ((size_t)bh * SEQ + jt * 64 + r) * DIMH + lc * 8,
                (char*)&Ks[buf][0] + it * 4096 + wbase);
      gld_lds16(vt + ((size_t)bh * DIMH + r) * SEQ + jt * 64 + lc * 8,
                (char*)&Vs[buf][0] + it * 4096 + wbase);
    }
  };

  stage(0, 0);
  __syncthreads();

  for (int jt = 0; jt < SEQ / 64; ++jt) {
    const int buf = jt & 1;
    if (jt + 1 < SEQ / 64) stage(jt + 1, buf ^ 1);

    // S^T = K Q^T : lane holds S[q=m*16+lm][kv = 16n + 4g + r]
    f32x4 sa[2][4];
#pragma unroll
    for (int m = 0; m < 2; ++m)
#pragma unroll
      for (int n = 0; n < 4; ++n) sa[m][n] = (f32x4){0.f, 0.f, 0.f, 0.f};
    __builtin_amdgcn_s_setprio(1);
#pragma unroll
    for (int kk = 0; kk < 2; ++kk)
#pragma unroll
      for (int n = 0; n < 4; ++n) {
        const int row = n * 16 + lm;
        const bf16x8 af = *(const bf16x8*)((const char*)&Ks[buf][0] + row * 128
                                           + (((kk * 4 + g) ^ (row & 7)) << 4));
#pragma unroll
        for (int m = 0; m < 2; ++m)
          sa[m][n] = __builtin_amdgcn_mfma_f32_16x16x32_bf16(af, qf[m][kk], sa[m][n], 0, 0, 0);
      }
    __builtin_amdgcn_s_setprio(0);

    // row max (2 shuffles per m)
    float mx[2];
#pragma unroll
    for (int m = 0; m < 2; ++m) {
      float a0 = fmaxf(fmaxf(sa[m][0][0], sa[m][0][1]), fmaxf(sa[m][0][2], sa[m][0][3]));
      float a1 = fmaxf(fmaxf(sa[m][1][0], sa[m][1][1]), fmaxf(sa[m][1][2], sa[m][1][3]));
      float a2 = fmaxf(fmaxf(sa[m][2][0], sa[m][2][1]), fmaxf(sa[m][2][2], sa[m][2][3]));
      float a3 = fmaxf(fmaxf(sa[m][3][0], sa[m][3][1]), fmaxf(sa[m][3][2], sa[m][3][3]));
      float a = fmaxf(fmaxf(a0, a1), fmaxf(a2, a3));
      a = fmaxf(a, __shfl_xor(a, 16));
      a = fmaxf(a, __shfl_xor(a, 32));
      mx[m] = a;
    }
    // defer-max: skip rescale unless some row's max grew by > 11 (exp2 units)
    const bool skip = __all((mx[0] <= mrow[0] + 11.0f) && (mx[1] <= mrow[1] + 11.0f));
    if (!skip) {
#pragma unroll
      for (int m = 0; m < 2; ++m) {
        const float m2   = fmaxf(mrow[m], mx[m]);
        const float corr = exp2f(mrow[m] - m2);
        mrow[m] = m2;
        lrow[m] *= corr;
        float c[4];
#pragma unroll
        for (int r = 0; r < 4; ++r) c[r] = __shfl(corr, g * 4 + r);
#pragma unroll
        for (int n = 0; n < 4; ++n)
#pragma unroll
          for (int r = 0; r < 4; ++r) ao[m][n][r] *= c[r];
      }
    }

    // P = exp2(S - m), row-sum, pack to A-fragments (all lane-local)
    bf16x8 pa[2][2];
#pragma unroll
    for (int m = 0; m < 2; ++m) {
      float rs = 0.f;
#pragma unroll
      for (int n = 0; n < 4; ++n)
#pragma unroll
        for (int r = 0; r < 4; ++r) {
          const float p = exp2f(sa[m][n][r] - mrow[m]);
          sa[m][n][r] = p;
          rs += p;
        }
      rs += __shfl_xor(rs, 16);
      rs += __shfl_xor(rs, 32);
      lrow[m] += rs;
#pragma unroll
      for (int h = 0; h < 2; ++h) {
        union { bf16x8 v8; short s[8]; } u;
#pragma unroll
        for (int n2 = 0; n2 < 2; ++n2)
#pragma unroll
          for (int r = 0; r < 4; ++r) {
            const bf16 bb = __float2bfloat16(sa[m][h * 2 + n2][r]);
            u.s[n2 * 4 + r] = *(const short*)&bb;
          }
        pa[m][h] = u.v8;
      }
    }

    // O += P V  (sigma-permuted V reads: k-slot 8g+j <-> kv {4g+j, 16+4g+j-4})
    __builtin_amdgcn_s_setprio(1);
#pragma unroll
    for (int n = 0; n < 4; ++n) {
      const int row = n * 16 + lm;
      const char* vb = (const char*)&Vs[buf][0] + row * 128;
      const int sw = row & 7;
#pragma unroll
      for (int kk = 0; kk < 2; ++kk) {
        const bf16x4 lo = *(const bf16x4*)(vb + (((kk * 4 + (g >> 1)) ^ sw) << 4) + (g & 1) * 8);
        const bf16x4 hi = *(const bf16x4*)(vb + (((kk * 4 + 2 + (g >> 1)) ^ sw) << 4) + (g & 1) * 8);
        const bf16x8 vf = __builtin_shufflevector(lo, hi, 0, 1, 2, 3, 4, 5, 6, 7);
#pragma unroll
        for (int m = 0; m < 2; ++m)
          ao[m][n] = __builtin_amdgcn_mfma_f32_16x16x32_bf16(pa[m][kk], vf, ao[m][n], 0, 0, 0);
      }
    }
    __builtin_amdgcn_s_setprio(0);
    __syncthreads();
  }

  // epilogue: normalize and store (row = q, col = d)
  const int batch = bh >> 4, head = bh & 15;
#pragma unroll
  for (int m = 0; m < 2; ++m) {
    const float linv = 1.0f / lrow[m];
    float lr[4];
#pragma unroll
    for (int r = 0; r < 4; ++r) lr[r] = __shfl(linv, g * 4 + r);
#pragma unroll
    for (int r = 0; r < 4; ++r) {
      const int row = qw + m * 16 + g * 4 + r;
#pragma unroll
      for (int n = 0; n < 4; ++n) {
        const int d = n * 16 + lm;
        out[((size_t)batch * SEQ + row) * INNER + head * DIMH + d] =
            __float2bfloat16(ao[m][n][r] * lr[r]);
      }
    }
  }
}

// ---------------------------------------------------------------------------
extern "C" void kernel_launch(void* const* d_in, const int* in_sizes, int n_in,
                              void* d_out, int out_size, void* d_ws, size_t ws_size,
                              hipStream_t stream)
{
  (void)in_sizes; (void)n_in; (void)out_size; (void)ws_size;
  const float* x_in = (const float*)d_in[0];
  const float* Wq   = (const float*)d_in[1];
  const float* Wkv  = (const float*)d_in[2];
  const float* Wo   = (const float*)d_in[3];
  const float* bo   = (const float*)d_in[4];
  const float* ln1g = (const float*)d_in[5];
  const float* ln1b = (const float*)d_in[6];
  const float* ln2g = (const float*)d_in[7];
  const float* ln2b = (const float*)d_in[8];
  const float* W1   = (const float*)d_in[9];
  const float* b1   = (const float*)d_in[10];
  const float* W2   = (const float*)d_in[11];
  const float* b2   = (const float*)d_in[12];
  float* xb = (float*)d_out;

  char* ws = (char*)d_ws;
  size_t off = 0;
  auto take = [&](size_t bytes) {
    char* p = ws + off;
    off += (bytes + 255) & ~(size_t)255;
    return p;
  };
  bf16* Wqkvt = (bf16*)take((size_t)DEPTH * 3072 * 1024 * 2);
  bf16* Wot   = (bf16*)take((size_t)DEPTH * 1024 * 1024 * 2);
  bf16* W1t   = (bf16*)take((size_t)DEPTH * 4096 * 1024 * 2);
  bf16* W2t   = (bf16*)take((size_t)DEPTH * 1024 * 4096 * 2);
  bf16* hb    = (bf16*)take((size_t)NTOK * DIM * 2);
  bf16* qbuf  = (bf16*)take((size_t)NTOK * INNER * 2);
  bf16* kbuf  = (bf16*)take((size_t)NTOK * INNER * 2);
  bf16* vtbuf = (bf16*)take((size_t)NTOK * INNER * 2);
  bf16* aobuf = (bf16*)take((size_t)NTOK * INNER * 2);
  bf16* h1buf = (bf16*)take((size_t)NTOK * DFF * 2);

  hipMemcpyAsync(xb, x_in, (size_t)NTOK * DIM * 4, hipMemcpyDeviceToDevice, stream);

  dim3 b256(256);
  transpose_convert<<<dim3(32, 32, DEPTH),  b256, 0, stream>>>(Wq,  Wqkvt, 1024, 1024, 0,    3072);
  transpose_convert<<<dim3(64, 32, DEPTH),  b256, 0, stream>>>(Wkv, Wqkvt, 1024, 2048, 1024, 3072);
  transpose_convert<<<dim3(32, 32, DEPTH),  b256, 0, stream>>>(Wo,  Wot,   1024, 1024, 0,    1024);
  transpose_convert<<<dim3(128, 32, DEPTH), b256, 0, stream>>>(W1,  W1t,   1024, 4096, 0,    4096);
  transpose_convert<<<dim3(32, 128, DEPTH), b256, 0, stream>>>(W2,  W2t,   4096, 1024, 0,    1024);

  for (int l = 0; l < DEPTH; ++l) {
    ln_kernel<<<NTOK, b256, 0, stream>>>(xb, ln1g + l * DIM, ln1b + l * DIM, hb);
    gemm128<0><<<dim3(3072 / 128, NTOK / 128), b256, 0, stream>>>(
        hb, Wqkvt + (size_t)l * 3072 * 1024, 3072, 1024,
        nullptr, nullptr, nullptr, qbuf, kbuf, vtbuf);
    attn_kernel<<<dim3(SEQ / 128, 32), b256, 0, stream>>>(qbuf, kbuf, vtbuf, aobuf);
    gemm128<1><<<dim3(1024 / 128, NTOK / 128), b256, 0, stream>>>(
        aobuf, Wot + (size_t)l * 1024 * 1024, 1024, 1024,
        bo + l * DIM, xb, nullptr, nullptr, nullptr, nullptr);
    ln_kernel<<<NTOK, b256, 0, stream>>>(xb, ln2g + l * DIM, ln2b + l * DIM, hb);
    gemm128<2><<<dim3(4096 / 128, NTOK / 128), b256, 0, stream>>>(
        hb, W1t + (size_t)l * 4096 * 1024, 4096, 1024,
        b1 + l * DFF, nullptr, h1buf, nullptr, nullptr, nullptr);
    gemm128<1><<<dim3(1024 / 128, NTOK / 128), b256, 0, stream>>>(
        h1buf, W2t + (size_t)l * 1024 * 4096, 1024, 4096,
        b2 + l * DIM, xb, nullptr, nullptr, nullptr, nullptr);
  }
}